// Round 3
// baseline (287.657 us; speedup 1.0000x reference)
//
#include <hip/hip_runtime.h>
#include <stdint.h>

// Problem: single attention head. B=4, T=2048, C=1024, H=64.
// Inputs: x[B,T,C], Wq[C,H], Wk[C,H], Wv[C,H]  (dtype fp32 OR bf16 — detected
// at runtime, see detect_dtype; both template variants are launched and the
// mismatched one early-exits).
// Outputs (concatenated, same dtype as inputs): out[B,T,H], k[B,T,H], v[B,T,H]
// scale = C^-0.5 = 1/32.
//
// Pipeline: detect_dtype -> prep_w (retile W to fp32 ws) -> qkv (q into
// out[0..NKV) as scratch, k/v final) -> attn (flash, base-2 online softmax,
// finite mask sentinel, overwrites out[0..NKV) with the result; each block
// reads only its own q rows before writing them — race-free).

#define NB 4
#define TT 2048
#define CC 1024
#define HH 64
#define NKV (NB * TT * HH) // 524288 elements per output tensor

__device__ __forceinline__ float bf2f(unsigned short u) {
    union { unsigned int i; float f; } v;
    v.i = ((unsigned int)u) << 16;
    return v.f;
}
__device__ __forceinline__ unsigned short f2bf(float f) {
    union { float f; unsigned int i; } v;
    v.f = f;
    unsigned int r = v.i + 0x7fffu + ((v.i >> 16) & 1u); // RNE
    return (unsigned short)(r >> 16);
}

template <bool BF16>
__device__ __forceinline__ float4 load4(const void* p, size_t i) {
    if (BF16) {
        ushort4 u = *(const ushort4*)((const unsigned short*)p + i);
        float4 f;
        f.x = bf2f(u.x); f.y = bf2f(u.y); f.z = bf2f(u.z); f.w = bf2f(u.w);
        return f;
    } else {
        return *(const float4*)((const float*)p + i);
    }
}
template <bool BF16>
__device__ __forceinline__ float load1(const void* p, size_t i) {
    return BF16 ? bf2f(((const unsigned short*)p)[i]) : ((const float*)p)[i];
}
template <bool BF16>
__device__ __forceinline__ void store1(void* p, size_t i, float v) {
    if (BF16) ((unsigned short*)p)[i] = f2bf(v);
    else ((float*)p)[i] = v;
}
template <bool BF16>
__device__ __forceinline__ void store4(void* p, size_t i, float4 v) {
    if (BF16) {
        ushort4 u;
        u.x = f2bf(v.x); u.y = f2bf(v.y); u.z = f2bf(v.z); u.w = f2bf(v.w);
        *(ushort4*)((unsigned short*)p + i) = u;
    } else {
        *(float4*)((float*)p + i) = v;
    }
}

// ---------------------------------------------------------------------------
// Dtype detection. True-bf16 N(0,1) data: every 2-byte pair is a bf16 with
// exponent near 127. fp32 data read as 2-byte pairs: the low-half pairs have
// uniform-random exponent bits -> ~42% of pairs land outside [2^-20, 2^20] or
// are Inf/NaN. flag: 1 = bf16, 0 = fp32.
// ---------------------------------------------------------------------------
__global__ __launch_bounds__(256) void detect_dtype(const unsigned short* __restrict__ xb,
                                                    unsigned int* __restrict__ flag) {
    __shared__ int cnt;
    if (threadIdx.x == 0) cnt = 0;
    __syncthreads();
    int bad = 0;
    for (int i = 0; i < 4; ++i) {
        unsigned short u = xb[threadIdx.x * 4 + i];
        int e = (u >> 7) & 0xFF;
        if (e == 0xFF || e < 107 || e > 147) ++bad;
    }
    atomicAdd(&cnt, bad);
    __syncthreads();
    if (threadIdx.x == 0) *flag = (cnt < 100) ? 1u : 0u;
}

// ---------------------------------------------------------------------------
// prep_w: widen/copy W to fp32, retile to Wt2[m][cb][h][cc] (cb=c/4, cc=c%4)
// so the QKV GEMM loads per-lane-contiguous float4 weights (lanes = h).
// ---------------------------------------------------------------------------
template <bool BF16>
__global__ __launch_bounds__(256) void prep_w(const void* __restrict__ Wq,
                                              const void* __restrict__ Wk,
                                              const void* __restrict__ Wv,
                                              float* __restrict__ Wt2,
                                              const unsigned int* __restrict__ flag) {
    if (*flag != (BF16 ? 1u : 0u)) return;
    int gid = blockIdx.x * 256 + threadIdx.x; // 0 .. 196607
    int m   = gid >> 16;
    int rem = gid & 65535;
    int cb  = rem >> 8;
    int h   = (rem >> 2) & 63;
    int cc  = rem & 3;
    const void* W = (m == 0) ? Wq : (m == 1) ? Wk : Wv;
    Wt2[gid] = load1<BF16>(W, (size_t)(cb * 4 + cc) * HH + h);
}

// ---------------------------------------------------------------------------
// QKV projection. 512 blocks x 256 threads, 16 rows/block staged in 64KB LDS
// fp32. Thread t: h = t&63, rows (t>>6)*4 ..+3. 12 accumulators.
// Writes (native dtype): q -> out[0..NKV) (scratch), k, v -> final slots.
// ---------------------------------------------------------------------------
template <bool BF16>
__global__ __launch_bounds__(256) void qkv_kernel(const void* __restrict__ x,
                                                  const float* __restrict__ Wt2,
                                                  void* __restrict__ out,
                                                  const unsigned int* __restrict__ flag) {
    if (*flag != (BF16 ? 1u : 0u)) return;
    __shared__ float xs[16 * 1024]; // 64KB
    const int t    = threadIdx.x;
    const int row0 = blockIdx.x * 16;

    for (int i = 0; i < 16; ++i)
        *(float4*)&xs[i * 1024 + 4 * t] = load4<BF16>(x, (size_t)(row0 + i) * CC + 4 * t);
    __syncthreads();

    const int h  = t & 63;
    const int i0 = (t >> 6) * 4;

    float aq[4] = {0.f, 0.f, 0.f, 0.f};
    float ak[4] = {0.f, 0.f, 0.f, 0.f};
    float av[4] = {0.f, 0.f, 0.f, 0.f};

    const float* wqb = Wt2 + ((size_t)h << 2);
    const float* wkb = wqb + 65536;
    const float* wvb = wkb + 65536;

#pragma unroll 4
    for (int cb = 0; cb < 256; ++cb) {
        const int c = cb * 4;
        float4 wq = *(const float4*)(wqb + (size_t)cb * 256);
        float4 wk = *(const float4*)(wkb + (size_t)cb * 256);
        float4 wv = *(const float4*)(wvb + (size_t)cb * 256);
#pragma unroll
        for (int r = 0; r < 4; ++r) {
            float4 xv = *(const float4*)&xs[(i0 + r) * 1024 + c];
            aq[r] = fmaf(xv.x, wq.x, fmaf(xv.y, wq.y, fmaf(xv.z, wq.z, fmaf(xv.w, wq.w, aq[r]))));
            ak[r] = fmaf(xv.x, wk.x, fmaf(xv.y, wk.y, fmaf(xv.z, wk.z, fmaf(xv.w, wk.w, ak[r]))));
            av[r] = fmaf(xv.x, wv.x, fmaf(xv.y, wv.y, fmaf(xv.z, wv.z, fmaf(xv.w, wv.w, av[r]))));
        }
    }

#pragma unroll
    for (int r = 0; r < 4; ++r) {
        size_t row = (size_t)(row0 + i0 + r);
        store1<BF16>(out, row * HH + h, aq[r]);           // q (scratch)
        store1<BF16>(out, NKV + row * HH + h, ak[r]);     // k output
        store1<BF16>(out, 2 * NKV + row * HH + h, av[r]); // v output
    }
}

// ---------------------------------------------------------------------------
// Flash attention, base-2 online softmax, finite mask sentinel (-1e30f).
// Grid (64 q-tiles, 4 batches) x 256 threads. Q-tile = 32 rows, K-tile = 64.
// Thread t: rp=t>>4 -> rows 2rp, 2rp+1; cg=t&15.
//   score phase: cols j = cg + 16u (u=0..3); PV phase: dims d = 4cg..4cg+3.
// LDS ~50KB: Qs/Ps/Ks stride 68 (bank-spread), Vs stride 64.
// ---------------------------------------------------------------------------
#define LDQ 68
#define LDK 68

__device__ __forceinline__ void fma4(float (&acc)[4], float a, const float4 v) {
    acc[0] = fmaf(a, v.x, acc[0]);
    acc[1] = fmaf(a, v.y, acc[1]);
    acc[2] = fmaf(a, v.z, acc[2]);
    acc[3] = fmaf(a, v.w, acc[3]);
}

template <bool BF16>
__global__ __launch_bounds__(256) void attn_kernel(void* __restrict__ out,
                                                   const unsigned int* __restrict__ flag) {
    if (*flag != (BF16 ? 1u : 0u)) return;
    __shared__ float Qs[32 * LDQ];
    __shared__ float Ks[64 * LDK]; // [j][h]
    __shared__ float Vs[64 * 64];  // [j][d]
    __shared__ float Ps[32 * LDQ];

    const int t  = threadIdx.x;
    const int qt = blockIdx.x;
    const int b  = blockIdx.y;
    const int rp = t >> 4, cg = t & 15;
    const int r0 = rp * 2, r1 = r0 + 1;
    const int db = cg * 4;
    const int q0 = qt * 32;
    const int qrow0 = q0 + r0, qrow1 = q0 + r1;

    const float SC2 = 0.0450842200113808f; // (1/32)*log2(e)
    const float NEG_BIG = -1e30f;          // finite mask sentinel

    // load Q tile (32 x 64)
#pragma unroll
    for (int i = 0; i < 2; ++i) {
        int idx = i * 1024 + 4 * t;
        int r = idx >> 6, c = idx & 63;
        *(float4*)&Qs[r * LDQ + c] = load4<BF16>(out, (size_t)(b * TT + q0 + r) * HH + c);
    }

    float o0[4] = {0.f, 0.f, 0.f, 0.f}, o1[4] = {0.f, 0.f, 0.f, 0.f};
    float m0 = NEG_BIG, m1 = NEG_BIG, l0 = 0.f, l1 = 0.f;

    const int nkt = (q0 >> 6) + 1; // causal: K-tiles up to the diagonal

    for (int kt = 0; kt < nkt; ++kt) {
#pragma unroll
        for (int i = 0; i < 4; ++i) {
            int idx = i * 1024 + 4 * t;
            int a = idx >> 6, c = idx & 63;
            *(float4*)&Ks[a * LDK + c] =
                load4<BF16>(out, NKV + (size_t)(b * TT + kt * 64 + a) * HH + c);
            *(float4*)&Vs[a * 64 + c] =
                load4<BF16>(out, 2 * NKV + (size_t)(b * TT + kt * 64 + a) * HH + c);
        }
        __syncthreads(); // also covers Qs on first iteration

        float s0[4] = {0.f, 0.f, 0.f, 0.f}, s1[4] = {0.f, 0.f, 0.f, 0.f};
#pragma unroll 4
        for (int hh = 0; hh < 64; hh += 4) {
            float4 qa = *(const float4*)&Qs[r0 * LDQ + hh];
            float4 qb = *(const float4*)&Qs[r1 * LDQ + hh];
#pragma unroll
            for (int u = 0; u < 4; ++u) {
                float4 kv = *(const float4*)&Ks[(cg + 16 * u) * LDK + hh];
                s0[u] = fmaf(qa.x, kv.x, fmaf(qa.y, kv.y, fmaf(qa.z, kv.z, fmaf(qa.w, kv.w, s0[u]))));
                s1[u] = fmaf(qb.x, kv.x, fmaf(qb.y, kv.y, fmaf(qb.z, kv.z, fmaf(qb.w, kv.w, s1[u]))));
            }
        }

#pragma unroll
        for (int u = 0; u < 4; ++u) {
            int krow = kt * 64 + cg + 16 * u;
            s0[u] = (krow <= qrow0) ? s0[u] * SC2 : NEG_BIG;
            s1[u] = (krow <= qrow1) ? s1[u] * SC2 : NEG_BIG;
        }

        float tm0 = fmaxf(fmaxf(s0[0], s0[1]), fmaxf(s0[2], s0[3]));
        float tm1 = fmaxf(fmaxf(s1[0], s1[1]), fmaxf(s1[2], s1[3]));
#pragma unroll
        for (int off = 1; off < 16; off <<= 1) {
            tm0 = fmaxf(tm0, __shfl_xor(tm0, off));
            tm1 = fmaxf(tm1, __shfl_xor(tm1, off));
        }
        float mn0 = fmaxf(m0, tm0), mn1 = fmaxf(m1, tm1);
        float alpha0 = exp2f(m0 - mn0), alpha1 = exp2f(m1 - mn1);
        m0 = mn0; m1 = mn1;

        float p0[4], p1[4];
        float rs0 = 0.f, rs1 = 0.f;
#pragma unroll
        for (int u = 0; u < 4; ++u) {
            p0[u] = exp2f(s0[u] - mn0);
            p1[u] = exp2f(s1[u] - mn1);
            rs0 += p0[u];
            rs1 += p1[u];
        }
#pragma unroll
        for (int off = 1; off < 16; off <<= 1) {
            rs0 += __shfl_xor(rs0, off);
            rs1 += __shfl_xor(rs1, off);
        }
        l0 = l0 * alpha0 + rs0;
        l1 = l1 * alpha1 + rs1;

#pragma unroll
        for (int u = 0; u < 4; ++u) {
            Ps[r0 * LDQ + cg + 16 * u] = p0[u];
            Ps[r1 * LDQ + cg + 16 * u] = p1[u];
        }
        __syncthreads();

#pragma unroll
        for (int u = 0; u < 4; ++u) { o0[u] *= alpha0; o1[u] *= alpha1; }
#pragma unroll 4
        for (int j = 0; j < 64; j += 4) {
            float4 pa = *(const float4*)&Ps[r0 * LDQ + j];
            float4 pb = *(const float4*)&Ps[r1 * LDQ + j];
            float4 v0 = *(const float4*)&Vs[(j + 0) * 64 + db];
            float4 v1 = *(const float4*)&Vs[(j + 1) * 64 + db];
            float4 v2 = *(const float4*)&Vs[(j + 2) * 64 + db];
            float4 v3 = *(const float4*)&Vs[(j + 3) * 64 + db];
            fma4(o0, pa.x, v0); fma4(o1, pb.x, v0);
            fma4(o0, pa.y, v1); fma4(o1, pb.y, v1);
            fma4(o0, pa.z, v2); fma4(o1, pb.z, v2);
            fma4(o0, pa.w, v3); fma4(o1, pb.w, v3);
        }
        __syncthreads(); // before next tile overwrites Ks/Vs/Ps
    }

    const float inv0 = 1.f / l0, inv1 = 1.f / l1;
    float4 w0, w1;
    w0.x = o0[0] * inv0; w0.y = o0[1] * inv0; w0.z = o0[2] * inv0; w0.w = o0[3] * inv0;
    w1.x = o1[0] * inv1; w1.y = o1[1] * inv1; w1.z = o1[2] * inv1; w1.w = o1[3] * inv1;
    store4<BF16>(out, (size_t)(b * TT + qrow0) * HH + db, w0);
    store4<BF16>(out, (size_t)(b * TT + qrow1) * HH + db, w1);
}

// ---------------------------------------------------------------------------
// ws layout: [0,4) flag uint32; [256, 256+768KB) Wt2 fp32.
// ---------------------------------------------------------------------------
extern "C" void kernel_launch(void* const* d_in, const int* in_sizes, int n_in,
                              void* d_out, int out_size, void* d_ws, size_t ws_size,
                              hipStream_t stream) {
    const void* x  = d_in[0];
    const void* Wq = d_in[1];
    const void* Wk = d_in[2];
    const void* Wv = d_in[3];

    unsigned int* flag = (unsigned int*)d_ws;
    float* Wt2 = (float*)((char*)d_ws + 256);

    detect_dtype<<<1, 256, 0, stream>>>((const unsigned short*)x, flag);
    prep_w<false><<<768, 256, 0, stream>>>(Wq, Wk, Wv, Wt2, flag);
    prep_w<true><<<768, 256, 0, stream>>>(Wq, Wk, Wv, Wt2, flag);
    qkv_kernel<false><<<512, 256, 0, stream>>>(x, Wt2, d_out, flag);
    qkv_kernel<true><<<512, 256, 0, stream>>>(x, Wt2, d_out, flag);
    attn_kernel<false><<<dim3(64, 4), 256, 0, stream>>>(d_out, flag);
    attn_kernel<true><<<dim3(64, 4), 256, 0, stream>>>(d_out, flag);
}

// Round 8
// 269.924 us; speedup vs baseline: 1.0657x; 1.0657x over previous
//
#include <hip/hip_runtime.h>
#include <stdint.h>

// Single attention head. B=4, T=2048, C=1024, H=64.
// Inputs x,Wq,Wk,Wv; outputs concat (out,k,v) [B,T,H] each. scale = 1/32.
//
// DTYPE (R7 post-mortem): inputs are almost certainly fp32 (every bf16-only
// round NaN'd; R3's dual-path version passed). This file restores R3's
// structure EXACTLY: runtime dtype detection + both template variants, the
// mismatched one early-exits. rocprof dispatch durations will prove the live
// path (live qkv ~100us vs dead ~2us).
//
// Only change vs R3: attn q-tile 32 -> 16 rows (grid 128x4 = 512 blocks,
// 2/CU) to fix the 6%-occupancy latency bound in R3's counters.

#define NB 4
#define TT 2048
#define CC 1024
#define HH 64
#define NKV (NB * TT * HH)

__device__ __forceinline__ float bf2f(unsigned short u) {
    union { unsigned int i; float f; } v;
    v.i = ((unsigned int)u) << 16;
    return v.f;
}
__device__ __forceinline__ unsigned short f2bf(float f) {
    union { float f; unsigned int i; } v;
    v.f = f;
    unsigned int r = v.i + 0x7fffu + ((v.i >> 16) & 1u); // RNE
    return (unsigned short)(r >> 16);
}

template <bool BF16>
__device__ __forceinline__ float4 load4(const void* p, size_t i) {
    if (BF16) {
        ushort4 u = *(const ushort4*)((const unsigned short*)p + i);
        float4 f;
        f.x = bf2f(u.x); f.y = bf2f(u.y); f.z = bf2f(u.z); f.w = bf2f(u.w);
        return f;
    } else {
        return *(const float4*)((const float*)p + i);
    }
}
template <bool BF16>
__device__ __forceinline__ float load1(const void* p, size_t i) {
    return BF16 ? bf2f(((const unsigned short*)p)[i]) : ((const float*)p)[i];
}
template <bool BF16>
__device__ __forceinline__ void store1(void* p, size_t i, float v) {
    if (BF16) ((unsigned short*)p)[i] = f2bf(v);
    else ((float*)p)[i] = v;
}
template <bool BF16>
__device__ __forceinline__ void store4(void* p, size_t i, float4 v) {
    if (BF16) {
        ushort4 u;
        u.x = f2bf(v.x); u.y = f2bf(v.y); u.z = f2bf(v.z); u.w = f2bf(v.w);
        *(ushort4*)((unsigned short*)p + i) = u;
    } else {
        *(float4*)((float*)p + i) = v;
    }
}

// ---------------------------------------------------------------------------
// Dtype detection (R3-identical). flag: 1 = bf16, 0 = fp32.
// ---------------------------------------------------------------------------
__global__ __launch_bounds__(256) void detect_dtype(const unsigned short* __restrict__ xb,
                                                    unsigned int* __restrict__ flag) {
    __shared__ int cnt;
    if (threadIdx.x == 0) cnt = 0;
    __syncthreads();
    int bad = 0;
    for (int i = 0; i < 4; ++i) {
        unsigned short u = xb[threadIdx.x * 4 + i];
        int e = (u >> 7) & 0xFF;
        if (e == 0xFF || e < 107 || e > 147) ++bad;
    }
    atomicAdd(&cnt, bad);
    __syncthreads();
    if (threadIdx.x == 0) *flag = (cnt < 100) ? 1u : 0u;
}

// ---------------------------------------------------------------------------
// prep_w (R3-identical): widen/copy W to fp32, retile Wt2[m][cb][h][cc].
// ---------------------------------------------------------------------------
template <bool BF16>
__global__ __launch_bounds__(256) void prep_w(const void* __restrict__ Wq,
                                              const void* __restrict__ Wk,
                                              const void* __restrict__ Wv,
                                              float* __restrict__ Wt2,
                                              const unsigned int* __restrict__ flag) {
    if (*flag != (BF16 ? 1u : 0u)) return;
    int gid = blockIdx.x * 256 + threadIdx.x; // 0 .. 196607
    int m   = gid >> 16;
    int rem = gid & 65535;
    int cb  = rem >> 8;
    int h   = (rem >> 2) & 63;
    int cc  = rem & 3;
    const void* W = (m == 0) ? Wq : (m == 1) ? Wk : Wv;
    Wt2[gid] = load1<BF16>(W, (size_t)(cb * 4 + cc) * HH + h);
}

// ---------------------------------------------------------------------------
// QKV projection (R3-identical). 512 blocks x 256 threads, 16 rows/block.
// ---------------------------------------------------------------------------
template <bool BF16>
__global__ __launch_bounds__(256) void qkv_kernel(const void* __restrict__ x,
                                                  const float* __restrict__ Wt2,
                                                  void* __restrict__ out,
                                                  const unsigned int* __restrict__ flag) {
    if (*flag != (BF16 ? 1u : 0u)) return;
    __shared__ float xs[16 * 1024]; // 64KB
    const int t    = threadIdx.x;
    const int row0 = blockIdx.x * 16;

    for (int i = 0; i < 16; ++i)
        *(float4*)&xs[i * 1024 + 4 * t] = load4<BF16>(x, (size_t)(row0 + i) * CC + 4 * t);
    __syncthreads();

    const int h  = t & 63;
    const int i0 = (t >> 6) * 4;

    float aq[4] = {0.f, 0.f, 0.f, 0.f};
    float ak[4] = {0.f, 0.f, 0.f, 0.f};
    float av[4] = {0.f, 0.f, 0.f, 0.f};

    const float* wqb = Wt2 + ((size_t)h << 2);
    const float* wkb = wqb + 65536;
    const float* wvb = wkb + 65536;

#pragma unroll 4
    for (int cb = 0; cb < 256; ++cb) {
        const int c = cb * 4;
        float4 wq = *(const float4*)(wqb + (size_t)cb * 256);
        float4 wk = *(const float4*)(wkb + (size_t)cb * 256);
        float4 wv = *(const float4*)(wvb + (size_t)cb * 256);
#pragma unroll
        for (int r = 0; r < 4; ++r) {
            float4 xv = *(const float4*)&xs[(i0 + r) * 1024 + c];
            aq[r] = fmaf(xv.x, wq.x, fmaf(xv.y, wq.y, fmaf(xv.z, wq.z, fmaf(xv.w, wq.w, aq[r]))));
            ak[r] = fmaf(xv.x, wk.x, fmaf(xv.y, wk.y, fmaf(xv.z, wk.z, fmaf(xv.w, wk.w, ak[r]))));
            av[r] = fmaf(xv.x, wv.x, fmaf(xv.y, wv.y, fmaf(xv.z, wv.z, fmaf(xv.w, wv.w, av[r]))));
        }
    }

#pragma unroll
    for (int r = 0; r < 4; ++r) {
        size_t row = (size_t)(row0 + i0 + r);
        store1<BF16>(out, row * HH + h, aq[r]);           // q (scratch)
        store1<BF16>(out, NKV + row * HH + h, ak[r]);     // k output
        store1<BF16>(out, 2 * NKV + row * HH + h, av[r]); // v output
    }
}

// ---------------------------------------------------------------------------
// Flash attention (R3 logic, q-tile 16). Grid (128 q-tiles, 4 batches) x 256.
// Thread t: rp = t>>4 -> q row rp; cg = t&15.
//   score phase: cols j = cg + 16u (u=0..3); PV phase: dims d = 4cg..4cg+3.
// LDS 42.6KB: Qs/Ps [16][68], Ks [64][68], Vs [64][64].
// ---------------------------------------------------------------------------
#define LDQ 68
#define LDK 68

__device__ __forceinline__ void fma4(float (&acc)[4], float a, const float4 v) {
    acc[0] = fmaf(a, v.x, acc[0]);
    acc[1] = fmaf(a, v.y, acc[1]);
    acc[2] = fmaf(a, v.z, acc[2]);
    acc[3] = fmaf(a, v.w, acc[3]);
}

template <bool BF16>
__global__ __launch_bounds__(256) void attn_kernel(void* __restrict__ out,
                                                   const unsigned int* __restrict__ flag) {
    if (*flag != (BF16 ? 1u : 0u)) return;
    __shared__ float Qs[16 * LDQ];
    __shared__ float Ks[64 * LDK]; // [j][h]
    __shared__ float Vs[64 * 64];  // [j][d]
    __shared__ float Ps[16 * LDQ];

    const int t  = threadIdx.x;
    const int qt = blockIdx.x;
    const int b  = blockIdx.y;
    const int rp = t >> 4, cg = t & 15;
    const int db = cg * 4;
    const int q0 = qt * 16;
    const int qrow = q0 + rp;

    const float SC2 = 0.0450842200113808f; // (1/32)*log2(e)
    const float NEG_BIG = -1e30f;          // finite sentinel (proven R3)

    // load Q tile (16 x 64): 1024 elements = 256 threads x one float4
    {
        int idx = 4 * t;
        int r = idx >> 6, c = idx & 63;
        *(float4*)&Qs[r * LDQ + c] = load4<BF16>(out, (size_t)(b * TT + q0 + r) * HH + c);
    }

    float o0[4] = {0.f, 0.f, 0.f, 0.f};
    float m0 = NEG_BIG, l0 = 0.f;

    const int nkt = (q0 >> 6) + 1; // causal

    for (int kt = 0; kt < nkt; ++kt) {
#pragma unroll
        for (int i = 0; i < 4; ++i) {
            int idx = i * 1024 + 4 * t;
            int a = idx >> 6, c = idx & 63;
            *(float4*)&Ks[a * LDK + c] =
                load4<BF16>(out, NKV + (size_t)(b * TT + kt * 64 + a) * HH + c);
            *(float4*)&Vs[a * 64 + c] =
                load4<BF16>(out, 2 * NKV + (size_t)(b * TT + kt * 64 + a) * HH + c);
        }
        __syncthreads(); // also covers Qs on first iteration

        float s0[4] = {0.f, 0.f, 0.f, 0.f};
#pragma unroll 4
        for (int hh = 0; hh < 64; hh += 4) {
            float4 qa = *(const float4*)&Qs[rp * LDQ + hh];
#pragma unroll
            for (int u = 0; u < 4; ++u) {
                float4 kv = *(const float4*)&Ks[(cg + 16 * u) * LDK + hh];
                s0[u] = fmaf(qa.x, kv.x, fmaf(qa.y, kv.y, fmaf(qa.z, kv.z, fmaf(qa.w, kv.w, s0[u]))));
            }
        }

#pragma unroll
        for (int u = 0; u < 4; ++u) {
            int krow = kt * 64 + cg + 16 * u;
            s0[u] = (krow <= qrow) ? s0[u] * SC2 : NEG_BIG;
        }

        float tm0 = fmaxf(fmaxf(s0[0], s0[1]), fmaxf(s0[2], s0[3]));
#pragma unroll
        for (int off = 1; off < 16; off <<= 1)
            tm0 = fmaxf(tm0, __shfl_xor(tm0, off));
        float mn0 = fmaxf(m0, tm0);
        float alpha0 = exp2f(m0 - mn0);
        m0 = mn0;

        float p0[4];
        float rs0 = 0.f;
#pragma unroll
        for (int u = 0; u < 4; ++u) {
            p0[u] = exp2f(s0[u] - mn0);
            rs0 += p0[u];
        }
#pragma unroll
        for (int off = 1; off < 16; off <<= 1)
            rs0 += __shfl_xor(rs0, off);
        l0 = l0 * alpha0 + rs0;

#pragma unroll
        for (int u = 0; u < 4; ++u)
            Ps[rp * LDQ + cg + 16 * u] = p0[u];
        __syncthreads();

#pragma unroll
        for (int u = 0; u < 4; ++u) o0[u] *= alpha0;
#pragma unroll 4
        for (int j = 0; j < 64; j += 4) {
            float4 pa = *(const float4*)&Ps[rp * LDQ + j];
            float4 v0 = *(const float4*)&Vs[(j + 0) * 64 + db];
            float4 v1 = *(const float4*)&Vs[(j + 1) * 64 + db];
            float4 v2 = *(const float4*)&Vs[(j + 2) * 64 + db];
            float4 v3 = *(const float4*)&Vs[(j + 3) * 64 + db];
            fma4(o0, pa.x, v0);
            fma4(o0, pa.y, v1);
            fma4(o0, pa.z, v2);
            fma4(o0, pa.w, v3);
        }
        __syncthreads(); // before next tile overwrites Ks/Vs/Ps
    }

    const float inv0 = 1.f / l0;
    float4 w0;
    w0.x = o0[0] * inv0; w0.y = o0[1] * inv0;
    w0.z = o0[2] * inv0; w0.w = o0[3] * inv0;
    store4<BF16>(out, (size_t)(b * TT + qrow) * HH + db, w0);
}

// ---------------------------------------------------------------------------
// ws layout (R3-identical): [0,4) flag; [256, 256+768KB) Wt2 fp32.
// ---------------------------------------------------------------------------
extern "C" void kernel_launch(void* const* d_in, const int* in_sizes, int n_in,
                              void* d_out, int out_size, void* d_ws, size_t ws_size,
                              hipStream_t stream) {
    const void* x  = d_in[0];
    const void* Wq = d_in[1];
    const void* Wk = d_in[2];
    const void* Wv = d_in[3];

    unsigned int* flag = (unsigned int*)d_ws;
    float* Wt2 = (float*)((char*)d_ws + 256);

    detect_dtype<<<1, 256, 0, stream>>>((const unsigned short*)x, flag);
    prep_w<false><<<768, 256, 0, stream>>>(Wq, Wk, Wv, Wt2, flag);
    prep_w<true><<<768, 256, 0, stream>>>(Wq, Wk, Wv, Wt2, flag);
    qkv_kernel<false><<<512, 256, 0, stream>>>(x, Wt2, d_out, flag);
    qkv_kernel<true><<<512, 256, 0, stream>>>(x, Wt2, d_out, flag);
    attn_kernel<false><<<dim3(128, 4), 256, 0, stream>>>(d_out, flag);
    attn_kernel<true><<<dim3(128, 4), 256, 0, stream>>>(d_out, flag);
}